// Round 1
// baseline (282.622 us; speedup 1.0000x reference)
//
#include <hip/hip_runtime.h>
#include <math.h>

// Problem: capsule conv + dynamic routing, fused.
// x:    [B=32][H=32][W=32][IC=8][F=16]   (128 floats per pixel)
// wts:  [IC=8][ky=3][kx=3][cin=16][cout=128]   (cout = c*16+f)
// bias: [8][16] = 128 floats
// out:  [B][H][W][8][16] fp32
//
// Block: 256 threads = 2 groups x 128. Group g handles pixels wp=g*8..g*8+7 of a
// 16-wide row tile. Thread owns channel o=t&127; votes acc[i][p] live in VGPRs.

#define EPS 1e-7f

constexpr int TP = 16;              // pixels per block (along W)
constexpr int PATCH_COLS = TP + 2;  // 18 (halo)
constexpr int NT = 256;

__global__ __launch_bounds__(256, 2)
void capsule_fused_kernel(const float* __restrict__ x,
                          const float* __restrict__ wts,
                          const float* __restrict__ bias,
                          float* __restrict__ out)
{
    __shared__ float xs[3 * PATCH_COLS * 128];   // 27.6 KB input patch
    __shared__ float l_lds[2][8][8];             // logits [g][c][i]
    __shared__ float m_lds[2][8];                // softmax row max per i
    __shared__ float rd_lds[2][8];               // 1/denominator per i

    const int tid = threadIdx.x;
    const int g   = tid >> 7;      // group 0/1
    const int o   = tid & 127;     // out channel = c*16+f
    const int f   = o & 15;
    const int c   = o >> 4;

    const int bid = blockIdx.x;
    const int wt_ = bid & 1;           // which 16-wide tile
    const int h   = (bid >> 1) & 31;
    const int b   = bid >> 6;
    const int w0  = wt_ * TP;

    // ---- stage input patch rows h-1..h+1, cols w0-1..w0+16 ----
    for (int idx = tid; idx < 3 * PATCH_COLS * 128; idx += NT) {
        int e  = idx & 127;
        int rc = idx >> 7;
        int cc = rc % PATCH_COLS;
        int r  = rc / PATCH_COLS;
        int gh = h - 1 + r;
        int gw = w0 - 1 + cc;
        float v = 0.f;
        if ((unsigned)gh < 32u && (unsigned)gw < 32u)
            v = x[(((b * 32 + gh) * 32 + gw) << 7) + e];
        xs[idx] = v;
    }
    __syncthreads();

    // ---- conv: acc[i][p] = votes for input-capsule i, pixel wp=g*8+p, channel o
    float acc[8][8];
    #pragma unroll
    for (int i = 0; i < 8; ++i)
        #pragma unroll
        for (int p = 0; p < 8; ++p) acc[i][p] = 0.f;

    const float4* xs4 = (const float4*)xs;

    for (int dy = 0; dy < 3; ++dy) {
        for (int cin4 = 0; cin4 < 4; ++cin4) {   // 4 cin-quads
            #pragma unroll
            for (int i = 0; i < 8; ++i) {
                // 10 column vectors (cin4*4 .. +3) for this (dy, i)
                float4 xc[10];
                #pragma unroll
                for (int k = 0; k < 10; ++k)
                    xc[k] = xs4[(dy * PATCH_COLS + g * 8 + k) * 32 + i * 4 + cin4];
                #pragma unroll
                for (int dx = 0; dx < 3; ++dx) {
                    const float* wp_ = wts + ((((i * 3 + dy) * 3 + dx) * 16 + cin4 * 4) << 7) + o;
                    float w0v = wp_[0];
                    float w1v = wp_[128];
                    float w2v = wp_[256];
                    float w3v = wp_[384];
                    #pragma unroll
                    for (int p = 0; p < 8; ++p) {
                        float4 xv = xc[p + dx];
                        float a = acc[i][p];
                        a = fmaf(xv.x, w0v, a);
                        a = fmaf(xv.y, w1v, a);
                        a = fmaf(xv.z, w2v, a);
                        a = fmaf(xv.w, w3v, a);
                        acc[i][p] = a;
                    }
                }
            }
        }
    }

    // ---- dynamic routing (3 iters), per pixel ----
    const float bb = bias[o];
    const int lt = tid & 127;   // lane id within group

    #pragma unroll
    for (int p = 0; p < 8; ++p) {
        float v[8];
        #pragma unroll
        for (int i = 0; i < 8; ++i) v[i] = acc[i][p];

        float lg[8];
        #pragma unroll
        for (int i = 0; i < 8; ++i) lg[i] = 0.f;

        for (int it = 0; it < 3; ++it) {
            float pre;
            if (it == 0) {
                // softmax(0) = 1/8 uniform
                float s = 0.f;
                #pragma unroll
                for (int i = 0; i < 8; ++i) s += v[i];
                pre = s * 0.125f + bb;
            } else {
                __syncthreads();                 // prior readers of l/m/rd done
                if (f == 0) {
                    #pragma unroll
                    for (int i = 0; i < 8; ++i) l_lds[g][c][i] = lg[i];
                }
                __syncthreads();
                if (lt < 8) {                    // thread lt = capsule row i
                    int i = lt;
                    float m = l_lds[g][0][i];
                    for (int cc = 1; cc < 8; ++cc) m = fmaxf(m, l_lds[g][cc][i]);
                    float d = 0.f;
                    for (int cc = 0; cc < 8; ++cc) d += __expf(l_lds[g][cc][i] - m);
                    m_lds[g][i]  = m;
                    rd_lds[g][i] = 1.f / d;
                }
                __syncthreads();
                float s = 0.f;
                #pragma unroll
                for (int i = 0; i < 8; ++i) {
                    float r = __expf(lg[i] - m_lds[g][i]) * rd_lds[g][i];
                    s = fmaf(r, v[i], s);
                }
                pre = s + bb;
            }

            // squash over the 16 f-lanes
            float s2 = pre * pre;
            s2 += __shfl_xor(s2, 1);
            s2 += __shfl_xor(s2, 2);
            s2 += __shfl_xor(s2, 4);
            s2 += __shfl_xor(s2, 8);
            float scale = s2 / ((1.f + s2) * sqrtf(s2 + EPS));
            float act = scale * pre;

            if (it == 2) {
                int wp = g * 8 + p;
                out[(((b * 32 + h) * 32 + (w0 + wp)) << 7) + o] = act;
            } else {
                // agreement: lg[i] += sum_f v[i]*act  (same value on all 16 lanes)
                #pragma unroll
                for (int i = 0; i < 8; ++i) {
                    float a = v[i] * act;
                    a += __shfl_xor(a, 1);
                    a += __shfl_xor(a, 2);
                    a += __shfl_xor(a, 4);
                    a += __shfl_xor(a, 8);
                    lg[i] += a;
                }
            }
        }
    }
}

extern "C" void kernel_launch(void* const* d_in, const int* in_sizes, int n_in,
                              void* d_out, int out_size, void* d_ws, size_t ws_size,
                              hipStream_t stream) {
    const float* x    = (const float*)d_in[0];   // [32,32,32,8,16]
    const float* wts  = (const float*)d_in[1];   // [8,3,3,16,128]
    const float* bias = (const float*)d_in[2];   // [1,1,8,16] -> 128
    float* out        = (float*)d_out;           // [32,32,32,8,16]

    dim3 grid(2048);   // 32 b * 32 h * 2 w-tiles
    dim3 block(256);
    capsule_fused_kernel<<<grid, block, 0, stream>>>(x, wts, bias, out);
}

// Round 3
// 246.521 us; speedup vs baseline: 1.1464x; 1.1464x over previous
//
#include <hip/hip_runtime.h>
#include <math.h>

// Capsule conv + dynamic routing via bf16 MFMA (16x16x32).
// Precision: BOTH A (input) and B (weights) split into bf16 hi+lo;
// per K-step compute Ah*Bh + Al*Bh + Ah*Bl (drop Al*Bl, rel ~2^-16).
//
// x:    [B=32][H=32][W=32][128]  fp32 (128 = i*16+cin)
// wts:  [i=8][tap=9][cin=16][o=128] fp32 -> prep to w_hi/w_lo bf16 [i][c][f][k=160]
// out:  [B][H][W][128] fp32 (o = c*16+f)
//
// Main: grid = 1024 (b*32+h), block = 1024 = 16 waves = (Mt in 0..1) x (c in 0..7).
// MFMA tile: M=16 px, N=16 f, K=160 (tap*16+cin, zero-padded 144..159).
// C/D layout: f = lane&15, pixel = Mt*16 + (lane>>4)*4 + reg.

typedef short bf16x8 __attribute__((ext_vector_type(8)));
typedef float f32x4 __attribute__((ext_vector_type(4)));

#define EPS 1e-7f
constexpr int PSTRIDE = 136;   // 128 + 8 pad: stride 272B -> 2-way bank alias (free)
constexpr int WK = 160;        // padded K per input capsule
constexpr int W_ELEMS = 8 * 8 * 16 * WK;   // 163840 per (hi|lo)

__device__ __forceinline__ unsigned short bf16_rne(float f) {
    unsigned u = __float_as_uint(f);
    unsigned r = u + 0x7FFF + ((u >> 16) & 1);
    return (unsigned short)(r >> 16);
}

__global__ void prep_weights(const float* __restrict__ wts,
                             unsigned short* __restrict__ w_hi,
                             unsigned short* __restrict__ w_lo) {
    int n = blockIdx.x * 256 + threadIdx.x;        // 163840 threads
    if (n >= W_ELEMS) return;
    int cf = n & 127;          // o = c*16+f
    int ik = n >> 7;           // (i,k)
    int i = ik / WK;
    int k = ik - i * WK;
    int c = cf >> 4, f = cf & 15;
    float w = 0.f;
    if (k < 144) {
        int tap = k >> 4, cin = k & 15;
        w = wts[((i * 9 + tap) * 16 + cin) * 128 + cf];
    }
    unsigned short hi = bf16_rne(w);
    float hif = __uint_as_float((unsigned)hi << 16);
    unsigned short lo = bf16_rne(w - hif);
    int dst = ((i * 8 + c) * 16 + f) * WK + k;
    w_hi[dst] = hi;
    w_lo[dst] = lo;
}

__global__ __launch_bounds__(1024, 4)
void capsule_mfma_kernel(const float* __restrict__ x,
                         const unsigned short* __restrict__ w_hi,
                         const unsigned short* __restrict__ w_lo,
                         const float* __restrict__ bias,
                         float* __restrict__ out)
{
    __shared__ unsigned short patch_hi[3 * 34 * PSTRIDE];   // 27744 B
    __shared__ unsigned short patch_lo[3 * 34 * PSTRIDE];   // 27744 B
    __shared__ float lg_arr[32 * 8 * 8];                    // [px][i][c]
    __shared__ float r_arr[32 * 8 * 8];                     // [px][c][i]

    const int tid  = threadIdx.x;
    const int lane = tid & 63;
    const int wv   = tid >> 6;       // 0..15
    const int c    = wv & 7;
    const int Mt   = wv >> 3;
    const int fi   = lane & 15;      // f (B-frag n) and pixel-in-tile (A-frag m)
    const int quad = lane >> 4;

    const int bid = blockIdx.x;
    const int h = bid & 31, b = bid >> 5;

    // ---- stage input patch rows h-1..h+1, cols -1..32, as bf16 hi+lo ----
    const float4* x4 = (const float4*)x;
    for (int idx = tid; idx < 102 * 32; idx += 1024) {
        int ch4  = idx & 31;
        int slot = idx >> 5;           // row*34 + colp
        int row  = slot / 34;
        int colp = slot - row * 34;
        int gh = h - 1 + row;
        int gw = colp - 1;
        float4 v = {0.f, 0.f, 0.f, 0.f};
        if ((unsigned)gh < 32u && (unsigned)gw < 32u)
            v = x4[(((b * 32 + gh) * 32 + gw) << 5) + ch4];
        ushort4 ph, pl;
        ph.x = bf16_rne(v.x); ph.y = bf16_rne(v.y);
        ph.z = bf16_rne(v.z); ph.w = bf16_rne(v.w);
        pl.x = bf16_rne(v.x - __uint_as_float((unsigned)ph.x << 16));
        pl.y = bf16_rne(v.y - __uint_as_float((unsigned)ph.y << 16));
        pl.z = bf16_rne(v.z - __uint_as_float((unsigned)ph.z << 16));
        pl.w = bf16_rne(v.w - __uint_as_float((unsigned)ph.w << 16));
        *(ushort4*)&patch_hi[slot * PSTRIDE + ch4 * 4] = ph;
        *(ushort4*)&patch_lo[slot * PSTRIDE + ch4 * 4] = pl;
    }
    __syncthreads();

    // ---- per-lane A offsets for the 5 K-steps ----
    // k = q*32 + quad*8 + j ; tap = 2q + (quad>>1); cin0 = (quad&1)*8
    // q=4, quads 2,3 -> tap 9 (pad): clamp to tap 8; B is zero there.
    int a_off[5];
    #pragma unroll
    for (int q = 0; q < 5; ++q) {
        int tap = 2 * q + (quad >> 1);
        if (tap > 8) tap = 8;
        int dy = tap / 3, dx = tap - dy * 3;
        a_off[q] = (dy * 34 + (Mt * 16 + fi + dx)) * PSTRIDE + (quad & 1) * 8;
    }

    // ---- conv via MFMA: acc[i] = votes tile for input capsule i ----
    f32x4 acc[8];
    #pragma unroll
    for (int i = 0; i < 8; ++i) acc[i] = (f32x4){0.f, 0.f, 0.f, 0.f};

    const int bbase = (c * 16 + fi) * WK + quad * 8;
    #pragma unroll
    for (int q = 0; q < 5; ++q) {
        #pragma unroll
        for (int i = 0; i < 8; ++i) {
            int boff = bbase + i * (8 * 16 * WK) + q * 32;
            bf16x8 bh = *(const bf16x8*)(w_hi + boff);
            bf16x8 bl = *(const bf16x8*)(w_lo + boff);
            bf16x8 ah = *(const bf16x8*)(patch_hi + a_off[q] + i * 16);
            bf16x8 al = *(const bf16x8*)(patch_lo + a_off[q] + i * 16);
            acc[i] = __builtin_amdgcn_mfma_f32_16x16x32_bf16(ah, bh, acc[i], 0, 0, 0);
            acc[i] = __builtin_amdgcn_mfma_f32_16x16x32_bf16(al, bh, acc[i], 0, 0, 0);
            acc[i] = __builtin_amdgcn_mfma_f32_16x16x32_bf16(ah, bl, acc[i], 0, 0, 0);
        }
    }

    // ---- dynamic routing ----
    const float bb  = bias[c * 16 + fi];
    const int   px0 = Mt * 16 + quad * 4;      // pixel of reg r is px0 + r

    float lg[8][4];
    float act[4];

    // iter 0: route = 1/8 uniform
    #pragma unroll
    for (int r = 0; r < 4; ++r) {
        float s = 0.f;
        #pragma unroll
        for (int i = 0; i < 8; ++i) s += acc[i][r];
        float pre = s * 0.125f + bb;
        float s2 = pre * pre;
        s2 += __shfl_xor(s2, 1); s2 += __shfl_xor(s2, 2);
        s2 += __shfl_xor(s2, 4); s2 += __shfl_xor(s2, 8);
        float scale = s2 / ((1.f + s2) * sqrtf(s2 + EPS));
        act[r] = scale * pre;
    }
    #pragma unroll
    for (int i = 0; i < 8; ++i)
        #pragma unroll
        for (int r = 0; r < 4; ++r) {
            float a = acc[i][r] * act[r];
            a += __shfl_xor(a, 1); a += __shfl_xor(a, 2);
            a += __shfl_xor(a, 4); a += __shfl_xor(a, 8);
            lg[i][r] = a;
        }
    if (fi == 0) {
        #pragma unroll
        for (int r = 0; r < 4; ++r)
            #pragma unroll
            for (int i = 0; i < 8; ++i)
                lg_arr[((px0 + r) * 8 + i) * 8 + c] = lg[i][r];
    }
    __syncthreads();
    if (tid < 256) {   // softmax over c for each (px, i)
        int p = tid >> 3, i = tid & 7;
        const float* lrow = &lg_arr[(p * 8 + i) * 8];
        float m = lrow[0];
        #pragma unroll
        for (int cc = 1; cc < 8; ++cc) m = fmaxf(m, lrow[cc]);
        float e[8]; float den = 0.f;
        #pragma unroll
        for (int cc = 0; cc < 8; ++cc) { e[cc] = __expf(lrow[cc] - m); den += e[cc]; }
        float rd = 1.f / den;
        #pragma unroll
        for (int cc = 0; cc < 8; ++cc) r_arr[(p * 8 + cc) * 8 + i] = e[cc] * rd;
    }
    __syncthreads();

    // iter 1
    #pragma unroll
    for (int r = 0; r < 4; ++r) {
        const float* rr = &r_arr[((px0 + r) * 8 + c) * 8];
        float s = 0.f;
        #pragma unroll
        for (int i = 0; i < 8; ++i) s = fmaf(rr[i], acc[i][r], s);
        float pre = s + bb;
        float s2 = pre * pre;
        s2 += __shfl_xor(s2, 1); s2 += __shfl_xor(s2, 2);
        s2 += __shfl_xor(s2, 4); s2 += __shfl_xor(s2, 8);
        float scale = s2 / ((1.f + s2) * sqrtf(s2 + EPS));
        act[r] = scale * pre;
    }
    #pragma unroll
    for (int i = 0; i < 8; ++i)
        #pragma unroll
        for (int r = 0; r < 4; ++r) {
            float a = acc[i][r] * act[r];
            a += __shfl_xor(a, 1); a += __shfl_xor(a, 2);
            a += __shfl_xor(a, 4); a += __shfl_xor(a, 8);
            lg[i][r] += a;
        }
    if (fi == 0) {
        #pragma unroll
        for (int r = 0; r < 4; ++r)
            #pragma unroll
            for (int i = 0; i < 8; ++i)
                lg_arr[((px0 + r) * 8 + i) * 8 + c] = lg[i][r];
    }
    __syncthreads();
    if (tid < 256) {
        int p = tid >> 3, i = tid & 7;
        const float* lrow = &lg_arr[(p * 8 + i) * 8];
        float m = lrow[0];
        #pragma unroll
        for (int cc = 1; cc < 8; ++cc) m = fmaxf(m, lrow[cc]);
        float e[8]; float den = 0.f;
        #pragma unroll
        for (int cc = 0; cc < 8; ++cc) { e[cc] = __expf(lrow[cc] - m); den += e[cc]; }
        float rd = 1.f / den;
        #pragma unroll
        for (int cc = 0; cc < 8; ++cc) r_arr[(p * 8 + cc) * 8 + i] = e[cc] * rd;
    }
    __syncthreads();

    // iter 2: final activation -> out
    #pragma unroll
    for (int r = 0; r < 4; ++r) {
        const float* rr = &r_arr[((px0 + r) * 8 + c) * 8];
        float s = 0.f;
        #pragma unroll
        for (int i = 0; i < 8; ++i) s = fmaf(rr[i], acc[i][r], s);
        float pre = s + bb;
        float s2 = pre * pre;
        s2 += __shfl_xor(s2, 1); s2 += __shfl_xor(s2, 2);
        s2 += __shfl_xor(s2, 4); s2 += __shfl_xor(s2, 8);
        float scale = s2 / ((1.f + s2) * sqrtf(s2 + EPS));
        int px = px0 + r;
        out[(((b * 32 + h) * 32 + px) << 7) + c * 16 + fi] = scale * pre;
    }
}

extern "C" void kernel_launch(void* const* d_in, const int* in_sizes, int n_in,
                              void* d_out, int out_size, void* d_ws, size_t ws_size,
                              hipStream_t stream) {
    const float* x    = (const float*)d_in[0];
    const float* wts  = (const float*)d_in[1];
    const float* bias = (const float*)d_in[2];
    float* out        = (float*)d_out;

    unsigned short* w_hi = (unsigned short*)d_ws;
    unsigned short* w_lo = w_hi + W_ELEMS;

    prep_weights<<<dim3(640), dim3(256), 0, stream>>>(wts, w_hi, w_lo);
    capsule_mfma_kernel<<<dim3(1024), dim3(1024), 0, stream>>>(x, w_hi, w_lo, bias, out);
}

// Round 4
// 141.224 us; speedup vs baseline: 2.0012x; 1.7456x over previous
//
#include <hip/hip_runtime.h>
#include <math.h>

// Capsule conv + dynamic routing via bf16 MFMA (16x16x32), A and B split bf16 hi+lo
// (Ah*Bh + Al*Bh + Ah*Bl; Al*Bl dropped, rel ~2^-16).
//
// x:    [B=32][H=32][W=32][128]  fp32 (128 = i*16+cin)
// wts:  [i=8][tap=9][cin=16][o=128] fp32 -> prep to lane-ordered bf16:
//       w[(i*5+q)][c][lane=quad*16+fi][j]  (k = q*32+quad*8+j, zero for k>=144)
//       so a wave's B-frag load is ONE contiguous 1KB transaction.
// out:  [B][H][W][128] fp32 (o = c*16+f)
//
// Main: grid=1024 (b*32+h), block=1024 = 16 waves = (Mt 0..1) x (c 0..7).
// MFMA tile M=16 px, N=16 f, K=160. C/D: f=lane&15, px = Mt*16 + (lane>>4)*4 + reg.
// Routing state (logits) lives ONLY in LDS (it is lane-redundant); 16-lane f-reductions
// via DPP row_ror (VALU pipe), softmax-over-c via padded LDS (stride 76/9: <=2-way).

typedef short bf16x8 __attribute__((ext_vector_type(8)));
typedef float f32x4 __attribute__((ext_vector_type(4)));

#define EPS 1e-7f
constexpr int PSTRIDE = 136;   // ushorts; 272B lane stride -> 2-way bank alias (free)
constexpr int LSTRIDE = 76;    // dwords per pixel in lg/r arrays (76 % 32 = 12)
constexpr int WK = 160;
constexpr int W_ELEMS = 40 * 8 * 64 * 8;   // 163840 per (hi|lo)

__device__ __forceinline__ unsigned short bf16_rne(float f) {
    unsigned u = __float_as_uint(f);
    unsigned r = u + 0x7FFF + ((u >> 16) & 1);
    return (unsigned short)(r >> 16);
}

template<int CTRL>
__device__ __forceinline__ float dpp_rot(float v) {
    int s = __float_as_int(v);
    return __int_as_float(__builtin_amdgcn_update_dpp(s, s, CTRL, 0xF, 0xF, false));
}
// sum over the 16-lane row (all lanes get the same total)
__device__ __forceinline__ float sum16(float v) {
    v += dpp_rot<0x128>(v);   // row_ror:8
    v += dpp_rot<0x124>(v);   // row_ror:4
    v += dpp_rot<0x122>(v);   // row_ror:2
    v += dpp_rot<0x121>(v);   // row_ror:1
    return v;
}

__global__ void prep_weights(const float* __restrict__ wts,
                             unsigned short* __restrict__ w_hi,
                             unsigned short* __restrict__ w_lo) {
    int n = blockIdx.x * 256 + threadIdx.x;        // 0..163839
    if (n >= W_ELEMS) return;
    int j    = n & 7;
    int lane = (n >> 3) & 63;
    int c    = (n >> 9) & 7;
    int iq   = n >> 12;            // i*5+q, 0..39
    int i    = iq / 5;
    int q    = iq - i * 5;
    int quad = lane >> 4, fi = lane & 15;
    int k = q * 32 + quad * 8 + j;
    float w = 0.f;
    if (k < 144) {
        int tap = k >> 4, cin = k & 15;
        w = wts[((i * 9 + tap) * 16 + cin) * 128 + c * 16 + fi];
    }
    unsigned short hi = bf16_rne(w);
    float hif = __uint_as_float((unsigned)hi << 16);
    unsigned short lo = bf16_rne(w - hif);
    w_hi[n] = hi;
    w_lo[n] = lo;
}

__global__ __launch_bounds__(1024, 4)
void capsule_mfma_kernel(const float* __restrict__ x,
                         const unsigned short* __restrict__ w_hi,
                         const unsigned short* __restrict__ w_lo,
                         const float* __restrict__ bias,
                         float* __restrict__ out)
{
    __shared__ unsigned short patch_hi[3 * 34 * PSTRIDE];   // 27744 B
    __shared__ unsigned short patch_lo[3 * 34 * PSTRIDE];   // 27744 B
    __shared__ float lg_arr[32 * LSTRIDE];                  // [px*76 + i*9 + c]
    __shared__ float r_arr[32 * LSTRIDE];                   // [px*76 + c*9 + i]

    const int tid  = threadIdx.x;
    const int lane = tid & 63;
    const int wv   = tid >> 6;
    const int c    = wv & 7;
    const int Mt   = wv >> 3;
    const int fi   = lane & 15;
    const int quad = lane >> 4;

    const int bid = blockIdx.x;
    const int h = bid & 31, b = bid >> 5;

    // ---- stage input patch rows h-1..h+1, cols -1..32, bf16 hi+lo ----
    const float4* x4 = (const float4*)x;
    for (int idx = tid; idx < 102 * 32; idx += 1024) {
        int ch4  = idx & 31;
        int slot = idx >> 5;
        int row  = slot / 34;
        int colp = slot - row * 34;
        int gh = h - 1 + row;
        int gw = colp - 1;
        float4 v = {0.f, 0.f, 0.f, 0.f};
        if ((unsigned)gh < 32u && (unsigned)gw < 32u)
            v = x4[(((b * 32 + gh) * 32 + gw) << 5) + ch4];
        ushort4 ph, pl;
        ph.x = bf16_rne(v.x); ph.y = bf16_rne(v.y);
        ph.z = bf16_rne(v.z); ph.w = bf16_rne(v.w);
        pl.x = bf16_rne(v.x - __uint_as_float((unsigned)ph.x << 16));
        pl.y = bf16_rne(v.y - __uint_as_float((unsigned)ph.y << 16));
        pl.z = bf16_rne(v.z - __uint_as_float((unsigned)ph.z << 16));
        pl.w = bf16_rne(v.w - __uint_as_float((unsigned)ph.w << 16));
        *(ushort4*)&patch_hi[slot * PSTRIDE + ch4 * 4] = ph;
        *(ushort4*)&patch_lo[slot * PSTRIDE + ch4 * 4] = pl;
    }
    __syncthreads();

    // ---- per-lane A offsets (k = q*32 + quad*8 + j; tap = 2q + (quad>>1)) ----
    int a_off[5];
    #pragma unroll
    for (int q = 0; q < 5; ++q) {
        int tap = 2 * q + (quad >> 1);
        if (tap > 8) tap = 8;                 // pad region: B is zero there
        int dy = tap / 3, dx = tap - dy * 3;
        a_off[q] = (dy * 34 + (Mt * 16 + fi + dx)) * PSTRIDE + (quad & 1) * 8;
    }

    // ---- conv via MFMA ----
    f32x4 acc[8];
    #pragma unroll
    for (int i = 0; i < 8; ++i) acc[i] = (f32x4){0.f, 0.f, 0.f, 0.f};

    const int lane8 = lane * 8;
    #pragma unroll
    for (int q = 0; q < 5; ++q) {
        #pragma unroll
        for (int i = 0; i < 8; ++i) {
            int boff = (i * 5 + q) * 4096 + c * 512 + lane8;
            bf16x8 bh = *(const bf16x8*)(w_hi + boff);
            bf16x8 bl = *(const bf16x8*)(w_lo + boff);
            bf16x8 ah = *(const bf16x8*)(patch_hi + a_off[q] + i * 16);
            bf16x8 al = *(const bf16x8*)(patch_lo + a_off[q] + i * 16);
            acc[i] = __builtin_amdgcn_mfma_f32_16x16x32_bf16(ah, bh, acc[i], 0, 0, 0);
            acc[i] = __builtin_amdgcn_mfma_f32_16x16x32_bf16(al, bh, acc[i], 0, 0, 0);
            acc[i] = __builtin_amdgcn_mfma_f32_16x16x32_bf16(ah, bl, acc[i], 0, 0, 0);
        }
    }

    // ---- dynamic routing ----
    const float bb  = bias[c * 16 + fi];
    const int   px0 = Mt * 16 + quad * 4;
    float act[4];

    // iter 0: route = 1/8 uniform
    #pragma unroll
    for (int r = 0; r < 4; ++r) {
        float s = 0.f;
        #pragma unroll
        for (int i = 0; i < 8; ++i) s += acc[i][r];
        float pre = s * 0.125f + bb;
        float s2 = sum16(pre * pre);
        float scale = s2 / ((1.f + s2) * sqrtf(s2 + EPS));
        act[r] = scale * pre;
    }
    // agreement -> lg_arr (initial write)
    #pragma unroll
    for (int i = 0; i < 8; ++i)
        #pragma unroll
        for (int r = 0; r < 4; ++r) {
            float a = sum16(acc[i][r] * act[r]);
            if (fi == 0) lg_arr[(px0 + r) * LSTRIDE + i * 9 + c] = a;
        }
    __syncthreads();
    if (tid < 256) {   // softmax over c for each (px, i)
        int p = tid >> 3, ii = tid & 7;
        const float* lrow = &lg_arr[p * LSTRIDE + ii * 9];
        float m = lrow[0];
        #pragma unroll
        for (int cc = 1; cc < 8; ++cc) m = fmaxf(m, lrow[cc]);
        float e[8]; float den = 0.f;
        #pragma unroll
        for (int cc = 0; cc < 8; ++cc) { e[cc] = __expf(lrow[cc] - m); den += e[cc]; }
        float rd = 1.f / den;
        #pragma unroll
        for (int cc = 0; cc < 8; ++cc) r_arr[p * LSTRIDE + cc * 9 + ii] = e[cc] * rd;
    }
    __syncthreads();

    // iter 1
    #pragma unroll
    for (int r = 0; r < 4; ++r) {
        const float* rr = &r_arr[(px0 + r) * LSTRIDE + c * 9];
        float s = 0.f;
        #pragma unroll
        for (int i = 0; i < 8; ++i) s = fmaf(rr[i], acc[i][r], s);
        float pre = s + bb;
        float s2 = sum16(pre * pre);
        float scale = s2 / ((1.f + s2) * sqrtf(s2 + EPS));
        act[r] = scale * pre;
    }
    #pragma unroll
    for (int i = 0; i < 8; ++i)
        #pragma unroll
        for (int r = 0; r < 4; ++r) {
            float a = sum16(acc[i][r] * act[r]);
            if (fi == 0) lg_arr[(px0 + r) * LSTRIDE + i * 9 + c] += a;
        }
    __syncthreads();
    if (tid < 256) {
        int p = tid >> 3, ii = tid & 7;
        const float* lrow = &lg_arr[p * LSTRIDE + ii * 9];
        float m = lrow[0];
        #pragma unroll
        for (int cc = 1; cc < 8; ++cc) m = fmaxf(m, lrow[cc]);
        float e[8]; float den = 0.f;
        #pragma unroll
        for (int cc = 0; cc < 8; ++cc) { e[cc] = __expf(lrow[cc] - m); den += e[cc]; }
        float rd = 1.f / den;
        #pragma unroll
        for (int cc = 0; cc < 8; ++cc) r_arr[p * LSTRIDE + cc * 9 + ii] = e[cc] * rd;
    }
    __syncthreads();

    // iter 2: final activation -> out
    #pragma unroll
    for (int r = 0; r < 4; ++r) {
        const float* rr = &r_arr[(px0 + r) * LSTRIDE + c * 9];
        float s = 0.f;
        #pragma unroll
        for (int i = 0; i < 8; ++i) s = fmaf(rr[i], acc[i][r], s);
        float pre = s + bb;
        float s2 = sum16(pre * pre);
        float scale = s2 / ((1.f + s2) * sqrtf(s2 + EPS));
        int px = px0 + r;
        out[(((b * 32 + h) * 32 + px) << 7) + c * 16 + fi] = scale * pre;
    }
}

extern "C" void kernel_launch(void* const* d_in, const int* in_sizes, int n_in,
                              void* d_out, int out_size, void* d_ws, size_t ws_size,
                              hipStream_t stream) {
    const float* x    = (const float*)d_in[0];
    const float* wts  = (const float*)d_in[1];
    const float* bias = (const float*)d_in[2];
    float* out        = (float*)d_out;

    unsigned short* w_hi = (unsigned short*)d_ws;
    unsigned short* w_lo = w_hi + W_ELEMS;

    prep_weights<<<dim3(640), dim3(256), 0, stream>>>(wts, w_hi, w_lo);
    capsule_mfma_kernel<<<dim3(1024), dim3(1024), 0, stream>>>(x, w_hi, w_lo, bias, out);
}